// Round 1
// baseline (735.071 us; speedup 1.0000x reference)
//
#include <hip/hip_runtime.h>

typedef __bf16 bf16;
typedef __bf16 bf16x4 __attribute__((ext_vector_type(4)));
typedef __bf16 bf16x8 __attribute__((ext_vector_type(8)));
typedef float f32x4 __attribute__((ext_vector_type(4)));

#define LOG2E 1.4426950408889634f

// ---------------------------------------------------------------------------
// Projection: Out = X @ W^T + bias.  X:[4096,1024] f32, W:[1024,1024] f32.
// z=0 -> Q' (bf16, [4096,1024]), z=1 -> K' (same), z=2 -> V'^T per head:
//   vt[(b*1024 + n)*2048 + s]   (n = h*64+d), so attention can read V^T rows
//   with contiguous s (kk) for the MFMA B-operand layout.
// ---------------------------------------------------------------------------
__global__ __launch_bounds__(256, 2)
void proj_kernel(const float* __restrict__ Xq, const float* __restrict__ Xk,
                 const float* __restrict__ Xv,
                 const float* __restrict__ Wq, const float* __restrict__ Wk,
                 const float* __restrict__ Wv,
                 const float* __restrict__ Bq, const float* __restrict__ Bk,
                 const float* __restrict__ Bv,
                 bf16* __restrict__ Oq, bf16* __restrict__ Ok,
                 bf16* __restrict__ Ov)
{
    const int z = blockIdx.z;
    const float* X  = (z == 0) ? Xq : (z == 1) ? Xk : Xv;
    const float* W  = (z == 0) ? Wq : (z == 1) ? Wk : Wv;
    const float* Bi = (z == 0) ? Bq : (z == 1) ? Bk : Bv;

    const int n0 = blockIdx.x * 128;
    const int m0 = blockIdx.y * 128;

    // +8 pad on 32-col rows: 40 elems -> 80B row stride, 16B-aligned frag reads,
    // <=2-way bank aliasing (free).
    __shared__ bf16 As[128 * 40];
    __shared__ bf16 Bs[128 * 40];

    const int t = threadIdx.x;
    const int w = t >> 6, l = t & 63, quad = l >> 4, ln = l & 15;
    const int wm = (w & 1) * 64, wn = (w >> 1) * 64;

    const f32x4 zero4 = {0.f, 0.f, 0.f, 0.f};
    f32x4 acc[4][4];
    for (int mi = 0; mi < 4; mi++)
        for (int ni = 0; ni < 4; ni++) acc[mi][ni] = zero4;

    for (int k0 = 0; k0 < 1024; k0 += 32) {
        // stage 128x32 fp32 -> bf16 tiles of X and W (coalesced float4 loads)
        for (int i = 0; i < 4; i++) {
            int idx = i * 256 + t;
            int row = idx >> 3, c4 = idx & 7;
            float4 a  = *(const float4*)&X[(size_t)(m0 + row) * 1024 + k0 + c4 * 4];
            float4 bb = *(const float4*)&W[(size_t)(n0 + row) * 1024 + k0 + c4 * 4];
            bf16x4 av, bv;
            av[0] = (bf16)a.x;  av[1] = (bf16)a.y;  av[2] = (bf16)a.z;  av[3] = (bf16)a.w;
            bv[0] = (bf16)bb.x; bv[1] = (bf16)bb.y; bv[2] = (bf16)bb.z; bv[3] = (bf16)bb.w;
            *(bf16x4*)&As[row * 40 + c4 * 4] = av;
            *(bf16x4*)&Bs[row * 40 + c4 * 4] = bv;
        }
        __syncthreads();

        bf16x8 af[4], bfv[4];
        for (int mi = 0; mi < 4; mi++)
            af[mi] = *(const bf16x8*)&As[(wm + mi * 16 + ln) * 40 + quad * 8];
        for (int ni = 0; ni < 4; ni++)
            bfv[ni] = *(const bf16x8*)&Bs[(wn + ni * 16 + ln) * 40 + quad * 8];
        for (int mi = 0; mi < 4; mi++)
            for (int ni = 0; ni < 4; ni++)
                acc[mi][ni] = __builtin_amdgcn_mfma_f32_16x16x32_bf16(
                    af[mi], bfv[ni], acc[mi][ni], 0, 0, 0);
        __syncthreads();
    }

    // epilogue: C/D layout col = ln, row = quad*4 + r
    bf16* Onat = (z == 0) ? Oq : Ok;
    for (int ni = 0; ni < 4; ni++) {
        int n = n0 + wn + ni * 16 + ln;
        float bias = Bi[n];
        for (int mi = 0; mi < 4; mi++) {
            int mbase = m0 + wm + mi * 16 + quad * 4;
            if (z < 2) {
                for (int r = 0; r < 4; r++)
                    Onat[(size_t)(mbase + r) * 1024 + n] = (bf16)(acc[mi][ni][r] + bias);
            } else {
                int b = mbase >> 11, s0 = mbase & 2047;
                bf16x4 vv;
                for (int r = 0; r < 4; r++) vv[r] = (bf16)(acc[mi][ni][r] + bias);
                *(bf16x4*)&Ov[(size_t)(b * 1024 + n) * 2048 + s0] = vv;
            }
        }
    }
}

// ---------------------------------------------------------------------------
// Fused flash attention that also streams raw (scale+mask) scores to d_out.
// Block = (q-tile of 128 rows, head h, batch b); 4 waves, wave w owns rows
// [w*32, w*32+32). K-tile BN=64 per iteration, 32 iterations.
// ---------------------------------------------------------------------------
__global__ __launch_bounds__(256, 2)
void attn_kernel(const bf16* __restrict__ Qp, const bf16* __restrict__ Kp,
                 const bf16* __restrict__ Vt, const float* __restrict__ mask,
                 float* __restrict__ ctx, float* __restrict__ scores)
{
    const int qt = blockIdx.x, h = blockIdx.y, b = blockIdx.z;
    const int q0 = qt * 128;
    const int t = threadIdx.x, w = t >> 6, l = t & 63, quad = l >> 4, ln = l & 15;

    __shared__ bf16 Qs[128 * 72];   // [q][d]   ld=72
    __shared__ bf16 Ks[64 * 72];    // [kk][d]  ld=72
    __shared__ bf16 VTs[64 * 72];   // [d][kk]  ld=72
    __shared__ bf16 Ps[128 * 72];   // [q][kk]  ld=72

    // stage Q tile [128 x 64] once
    for (int i = 0; i < 4; i++) {
        int idx = i * 256 + t;
        int row = idx >> 3, d8 = idx & 7;
        *(bf16x8*)&Qs[row * 72 + d8 * 8] =
            *(const bf16x8*)&Qp[(size_t)(b * 2048 + q0 + row) * 1024 + h * 64 + d8 * 8];
    }
    __syncthreads();

    // Q A-fragments held in registers for the whole block
    bf16x8 aq[2][2];
    for (int mi = 0; mi < 2; mi++)
        for (int ks = 0; ks < 2; ks++)
            aq[mi][ks] = *(const bf16x8*)&Qs[(w * 32 + mi * 16 + ln) * 72 + ks * 32 + quad * 8];

    const f32x4 zero4 = {0.f, 0.f, 0.f, 0.f};
    f32x4 O[2][4];
    for (int mi = 0; mi < 2; mi++)
        for (int ni = 0; ni < 4; ni++) O[mi][ni] = zero4;
    float mst[2][4], lst[2][4];
    for (int mi = 0; mi < 2; mi++)
        for (int r = 0; r < 4; r++) { mst[mi][r] = -1e30f; lst[mi][r] = 0.f; }

    const int srow_base = (b * 16 + h) * 2048 + q0 + w * 32;

    for (int kt = 0; kt < 32; kt++) {
        const int kk0 = kt * 64;
        __syncthreads();   // previous iteration's LDS reads complete
        // stage K tile [64 kk x 64 d] and V^T tile [64 d x 64 kk]
        for (int i = 0; i < 2; i++) {
            int idx = i * 256 + t;
            int row = idx >> 3, d8 = idx & 7;
            *(bf16x8*)&Ks[row * 72 + d8 * 8] =
                *(const bf16x8*)&Kp[(size_t)(b * 2048 + kk0 + row) * 1024 + h * 64 + d8 * 8];
            *(bf16x8*)&VTs[row * 72 + d8 * 8] =
                *(const bf16x8*)&Vt[(size_t)(b * 1024 + h * 64 + row) * 2048 + kk0 + d8 * 8];
        }
        __syncthreads();

        // S = Q K^T   (A: m=ln -> q, k=quad*8+j -> d; B: n=ln -> kk)
        f32x4 sa[2][4];
        for (int mi = 0; mi < 2; mi++)
            for (int ni = 0; ni < 4; ni++) sa[mi][ni] = zero4;
        for (int ks = 0; ks < 2; ks++) {
            bf16x8 kf[4];
            for (int ni = 0; ni < 4; ni++)
                kf[ni] = *(const bf16x8*)&Ks[(ni * 16 + ln) * 72 + ks * 32 + quad * 8];
            for (int mi = 0; mi < 2; mi++)
                for (int ni = 0; ni < 4; ni++)
                    sa[mi][ni] = __builtin_amdgcn_mfma_f32_16x16x32_bf16(
                        aq[mi][ks], kf[ni], sa[mi][ni], 0, 0, 0);
        }

        float maskv[4];
        for (int ni = 0; ni < 4; ni++)
            maskv[ni] = mask[b * 2048 + kk0 + ni * 16 + ln];

        // scale + mask, stream raw scores, per-row tile max
        float rmax[2][4];
        for (int mi = 0; mi < 2; mi++)
            for (int r = 0; r < 4; r++) rmax[mi][r] = -1e30f;
        for (int mi = 0; mi < 2; mi++) {
            for (int ni = 0; ni < 4; ni++) {
                int col = kk0 + ni * 16 + ln;
                for (int r = 0; r < 4; r++) {
                    float v = sa[mi][ni][r] * 0.125f + maskv[ni];
                    sa[mi][ni][r] = v;
                    scores[(size_t)(srow_base + mi * 16 + quad * 4 + r) * 2048 + col] = v;
                    rmax[mi][r] = fmaxf(rmax[mi][r], v);
                }
            }
        }
        // reduce row max across the 16-lane quad group
        for (int mi = 0; mi < 2; mi++)
            for (int r = 0; r < 4; r++) {
                float v = rmax[mi][r];
                v = fmaxf(v, __shfl_xor(v, 1));
                v = fmaxf(v, __shfl_xor(v, 2));
                v = fmaxf(v, __shfl_xor(v, 4));
                v = fmaxf(v, __shfl_xor(v, 8));
                rmax[mi][r] = v;
            }

        // online softmax update
        float alpha[2][4];
        for (int mi = 0; mi < 2; mi++)
            for (int r = 0; r < 4; r++) {
                float mnew = fmaxf(mst[mi][r], rmax[mi][r]);
                alpha[mi][r] = exp2f((mst[mi][r] - mnew) * LOG2E);
                mst[mi][r] = mnew;
            }

        float rsum[2][4];
        for (int mi = 0; mi < 2; mi++)
            for (int r = 0; r < 4; r++) rsum[mi][r] = 0.f;
        for (int mi = 0; mi < 2; mi++)
            for (int ni = 0; ni < 4; ni++)
                for (int r = 0; r < 4; r++) {
                    float p = exp2f((sa[mi][ni][r] - mst[mi][r]) * LOG2E);
                    rsum[mi][r] += p;
                    // P in A-operand friendly layout [q][kk]; same-wave rows only
                    Ps[(w * 32 + mi * 16 + quad * 4 + r) * 72 + ni * 16 + ln] = (bf16)p;
                }
        for (int mi = 0; mi < 2; mi++)
            for (int r = 0; r < 4; r++) {
                float v = rsum[mi][r];
                v += __shfl_xor(v, 1);
                v += __shfl_xor(v, 2);
                v += __shfl_xor(v, 4);
                v += __shfl_xor(v, 8);
                lst[mi][r] = lst[mi][r] * alpha[mi][r] + v;
            }

        // rescale O
        for (int mi = 0; mi < 2; mi++)
            for (int ni = 0; ni < 4; ni++)
                for (int r = 0; r < 4; r++) O[mi][ni][r] *= alpha[mi][r];

        // O += P V   (A: m=ln -> q, k -> kk; B: n=ln -> d, k -> kk from V^T)
        for (int ks = 0; ks < 2; ks++) {
            bf16x8 pf[2], vf[4];
            for (int mi = 0; mi < 2; mi++)
                pf[mi] = *(const bf16x8*)&Ps[(w * 32 + mi * 16 + ln) * 72 + ks * 32 + quad * 8];
            for (int ni = 0; ni < 4; ni++)
                vf[ni] = *(const bf16x8*)&VTs[(ni * 16 + ln) * 72 + ks * 32 + quad * 8];
            for (int mi = 0; mi < 2; mi++)
                for (int ni = 0; ni < 4; ni++)
                    O[mi][ni] = __builtin_amdgcn_mfma_f32_16x16x32_bf16(
                        pf[mi], vf[ni], O[mi][ni], 0, 0, 0);
        }
    }

    // epilogue: ctx = O / l
    for (int mi = 0; mi < 2; mi++)
        for (int ni = 0; ni < 4; ni++) {
            int n = h * 64 + ni * 16 + ln;
            for (int r = 0; r < 4; r++) {
                int row = b * 2048 + q0 + w * 32 + mi * 16 + quad * 4 + r;
                ctx[(size_t)row * 1024 + n] = O[mi][ni][r] / lst[mi][r];
            }
        }
}

extern "C" void kernel_launch(void* const* d_in, const int* in_sizes, int n_in,
                              void* d_out, int out_size, void* d_ws, size_t ws_size,
                              hipStream_t stream) {
    const float* q    = (const float*)d_in[0];
    const float* k    = (const float*)d_in[1];
    const float* v    = (const float*)d_in[2];
    const float* mask = (const float*)d_in[3];
    const float* Wq   = (const float*)d_in[4];
    const float* bq   = (const float*)d_in[5];
    const float* Wk   = (const float*)d_in[6];
    const float* bk   = (const float*)d_in[7];
    const float* Wv   = (const float*)d_in[8];
    const float* bv   = (const float*)d_in[9];

    bf16* Qp = (bf16*)d_ws;                 // [4096,1024]
    bf16* Kp = Qp + (size_t)4096 * 1024;    // [4096,1024]
    bf16* Vt = Kp + (size_t)4096 * 1024;    // [B*1024, 2048] = V'^T per head

    float* ctx    = (float*)d_out;                    // [2,2048,1024]
    float* scores = ctx + (size_t)2 * 2048 * 1024;    // [2,16,2048,2048]

    proj_kernel<<<dim3(8, 32, 3), 256, 0, stream>>>(
        q, k, v, Wq, Wk, Wv, bq, bk, bv, Qp, Kp, Vt);
    attn_kernel<<<dim3(16, 16, 2), 256, 0, stream>>>(
        Qp, Kp, Vt, mask, ctx, scores);
}